// Round 8
// baseline (441.485 us; speedup 1.0000x reference)
//
#include <hip/hip_runtime.h>

typedef unsigned int u32;
typedef unsigned long long u64;

#define T_ 4
#define B_ 32
#define E_ 1024
#define H_ 16
#define HD_ 64
#define CACHE_ 4096
#define S_ 4100
#define SPLIT_ 2
#define NROWS_ (CACHE_ / SPLIT_)      // rows per attn block = 2048
#define NCH_ (NROWS_ / 32)            // 32-row chunks = 64
#define NEGINF (-__builtin_inff())

// ---------------- mask dtype detection: 1 = bool bytes, 0 = int32 ----------------
__global__ void detect_mask(const unsigned char* __restrict__ m, int* __restrict__ flag) {
    __shared__ int cnt_s;
    if (threadIdx.x == 0) cnt_s = 0;
    __syncthreads();
    int cnt = 0;
    for (int i = threadIdx.x; i < 8192; i += 256) cnt += (m[i] != 0) ? 1 : 0;
#pragma unroll
    for (int off = 32; off; off >>= 1) cnt += __shfl_xor(cnt, off);
    if ((threadIdx.x & 63) == 0) atomicAdd(&cnt_s, cnt);
    __syncthreads();
    if (threadIdx.x == 0) *flag = (cnt_s > 2048) ? 1 : 0;
}

// ---------------- fused QKV projection (f32) ----------------
__global__ __launch_bounds__(256) void proj_kernel(
    const float* __restrict__ q,
    const float* __restrict__ Wq, const float* __restrict__ bq,
    const float* __restrict__ Wk, const float* __restrict__ bk,
    const float* __restrict__ Wv, const float* __restrict__ bv,
    float* __restrict__ qs, float* __restrict__ kn, float* __restrict__ vn)
{
    __shared__ float A_l[64][33];
    __shared__ float W_l[16][33];
    const int bx = blockIdx.x;
    const int mat = bx >> 7;
    const int rem = bx & 127;
    const int ct = rem >> 1, rt = rem & 1;
    const int c0 = ct * 16, r0 = rt * 64;
    const float* W    = (mat == 0) ? Wq : (mat == 1) ? Wk : Wv;
    const float* bias = (mat == 0) ? bq : (mat == 1) ? bk : bv;
    const int tid = threadIdx.x;
    const int row = tid & 63, cg = tid >> 6;
    float acc[4] = {0.f, 0.f, 0.f, 0.f};

    for (int k0 = 0; k0 < 1024; k0 += 32) {
        __syncthreads();
        for (int j = tid; j < 512; j += 256) {
            int ar = j >> 3, kk = (j & 7) * 4;
            float4 v = *(const float4*)(q + (size_t)(r0 + ar) * 1024 + k0 + kk);
            A_l[ar][kk] = v.x; A_l[ar][kk + 1] = v.y;
            A_l[ar][kk + 2] = v.z; A_l[ar][kk + 3] = v.w;
        }
        if (tid < 128) {
            int wr = tid >> 3, kk = (tid & 7) * 4;
            float4 v = *(const float4*)(W + (size_t)(c0 + wr) * 1024 + k0 + kk);
            W_l[wr][kk] = v.x; W_l[wr][kk + 1] = v.y;
            W_l[wr][kk + 2] = v.z; W_l[wr][kk + 3] = v.w;
        }
        __syncthreads();
#pragma unroll
        for (int kk = 0; kk < 32; kk++) {
            float a = A_l[row][kk];
#pragma unroll
            for (int j = 0; j < 4; j++) acc[j] += a * W_l[cg * 4 + j][kk];
        }
    }
    const int r = r0 + row;
    const int t = r >> 5, b = r & 31;
#pragma unroll
    for (int j = 0; j < 4; j++) {
        int c = c0 + cg * 4 + j;
        float val = acc[j] + bias[c];
        int h = c >> 6, d = c & 63;
        size_t oidx = ((size_t)((b * H_ + h) * T_ + t)) * HD_ + d;
        if (mat == 0) qs[oidx] = val * 0.125f;
        else if (mat == 1) kn[oidx] = val;
        else vn[oidx] = val;
    }
}

// ---------------- attention: sequential-streaming flash decode ----------------
// No compaction: all rows streamed in order (HW-prefetch-friendly), mask applied
// as -inf via bit-packed LDS mask (broadcast ds_read_b32 per chunk; no vmem op
// in the hot loop, so K/V vmcnt pipelining is undisturbed).
// Lane (r8 = l>>3, sub = l&7): row w*8+r8 of each 32-row chunk; dims {sub*4..+3}
// and {32+sub*4..+3} (8 lanes x 16B = 128B transaction per row per instr).
// Lane-local online softmax; single cross-r8 merge at kernel end.
__global__ __launch_bounds__(256, 4) void attn_kernel(
    const float* __restrict__ kcache, const float* __restrict__ vcache,
    const float* __restrict__ qs,
    const unsigned char* __restrict__ mask8, const int* __restrict__ flag,
    float* __restrict__ part_ml, float* __restrict__ part_acc)
{
    const int bid = blockIdx.x;
    const int bh = bid >> 1, split = bid & 1;
    const int b = bh >> 4;
    const int tid = threadIdx.x;
    const int w = tid >> 6, l = tid & 63;
    const int sub = l & 7, r8 = l >> 3;
    const int rowbit = w * 8 + r8;        // bit index within a chunk's mask word
    const int mode = *flag;
    const int* mask32 = (const int*)mask8;
    const int base0 = split * NROWS_;

    __shared__ float q_l[256];
    __shared__ u32 mbits[NCH_];           // 1 bit per row, 1 word per 32-row chunk

    q_l[tid] = qs[bh * 256 + tid];
    // pack mask bits: round r covers rows [r*256, r*256+256), wave w owns 64 of them
#pragma unroll
    for (int r = 0; r < NROWS_ / 256; r++) {
        int i = r * 256 + tid;            // row within split
        size_t mi = (size_t)b * S_ + base0 + i;
        bool mk = mode ? (mask8[mi] != 0) : (mask32[mi] != 0);
        u64 bal = __ballot(mk);
        int widx = r * 8 + w * 2;
        if (l == 0)  mbits[widx]     = (u32)bal;
        if (l == 32) mbits[widx + 1] = (u32)(bal >> 32);
    }
    __syncthreads();

    // hoisted q: per t, dims {sub*4..+3} (qa) and {32+sub*4..+3} (qb)
    float4 qa[4], qb[4];
#pragma unroll
    for (int t = 0; t < 4; t++) {
        qa[t] = *(const float4*)&q_l[t * 64 + sub * 4];
        qb[t] = *(const float4*)&q_l[t * 64 + 32 + sub * 4];
    }

    float4 o0[4], o1[4];
#pragma unroll
    for (int t = 0; t < 4; t++) {
        o0[t] = make_float4(0.f, 0.f, 0.f, 0.f);
        o1[t] = make_float4(0.f, 0.f, 0.f, 0.f);
    }
    float m[4] = {NEGINF, NEGINF, NEGINF, NEGINF};
    float L[4] = {0.f, 0.f, 0.f, 0.f};

    // this lane's row stream: row(c) = base0 + c*32 + rowbit, sequential in c
    const float* kb = kcache + ((size_t)bh * CACHE_ + base0 + rowbit) * HD_ + sub * 4;
    const float* vb = vcache + ((size_t)bh * CACHE_ + base0 + rowbit) * HD_ + sub * 4;

    float4 kA0, kA1, vA0, vA1, kB0, kB1, vB0, vB1;

#define ISSUE(K0, K1, V0, V1, CC) {                                   \
        const float* kp_ = kb + ((size_t)(CC) << 11);                 \
        const float* vp_ = vb + ((size_t)(CC) << 11);                 \
        K0 = *(const float4*)kp_;  K1 = *(const float4*)(kp_ + 32);   \
        V0 = *(const float4*)vp_;  V1 = *(const float4*)(vp_ + 32);   \
    }

#define PROCESS(K0, K1, V0, V1, CC) {                                               \
        const bool msk_ = (mbits[CC] >> rowbit) & 1;                                \
        _Pragma("unroll")                                                           \
        for (int t = 0; t < 4; t++) {                                               \
            float part = qa[t].x * K0.x + qa[t].y * K0.y + qa[t].z * K0.z           \
                       + qa[t].w * K0.w + qb[t].x * K1.x + qb[t].y * K1.y           \
                       + qb[t].z * K1.z + qb[t].w * K1.w;                           \
            part += __shfl_xor(part, 1);                                            \
            part += __shfl_xor(part, 2);                                            \
            part += __shfl_xor(part, 4);                                            \
            float s = msk_ ? NEGINF : part;                                         \
            if (s > m[t] + 8.f) {       /* defer-max: rare rescale */               \
                float fac = __expf(m[t] - s);                                       \
                L[t] *= fac;                                                        \
                o0[t].x *= fac; o0[t].y *= fac; o0[t].z *= fac; o0[t].w *= fac;     \
                o1[t].x *= fac; o1[t].y *= fac; o1[t].z *= fac; o1[t].w *= fac;     \
                m[t] = s;                                                           \
            }                                                                       \
            float e = (s == NEGINF) ? 0.f : __expf(s - m[t]);                       \
            L[t] += e;                                                              \
            o0[t].x += e * V0.x; o0[t].y += e * V0.y;                               \
            o0[t].z += e * V0.z; o0[t].w += e * V0.w;                               \
            o1[t].x += e * V1.x; o1[t].y += e * V1.y;                               \
            o1[t].z += e * V1.z; o1[t].w += e * V1.w;                               \
        }                                                                           \
    }

    ISSUE(kA0, kA1, vA0, vA1, 0);
    ISSUE(kB0, kB1, vB0, vB1, 1);

    for (int c = 0; c < NCH_; c += 2) {
        PROCESS(kA0, kA1, vA0, vA1, c);
        if (c + 2 < NCH_) ISSUE(kA0, kA1, vA0, vA1, c + 2);
        PROCESS(kB0, kB1, vB0, vB1, c + 1);
        if (c + 3 < NCH_) ISSUE(kB0, kB1, vB0, vB1, c + 3);
    }
#undef ISSUE
#undef PROCESS

    // ---- end merge across the 8 r8-groups (lanes differ in bits 3,4,5) ----
    const int pidx = bid * 4 + w;           // [0, 4096)
#pragma unroll
    for (int t = 0; t < 4; t++) {
        float M = m[t];
        M = fmaxf(M, __shfl_xor(M, 8));
        M = fmaxf(M, __shfl_xor(M, 16));
        M = fmaxf(M, __shfl_xor(M, 32));
        float fac = (m[t] == NEGINF) ? 0.f : __expf(m[t] - M);
        float Lr = L[t] * fac;
        Lr += __shfl_xor(Lr, 8);
        Lr += __shfl_xor(Lr, 16);
        Lr += __shfl_xor(Lr, 32);
        float a0x = o0[t].x * fac, a0y = o0[t].y * fac,
              a0z = o0[t].z * fac, a0w = o0[t].w * fac;
        float a1x = o1[t].x * fac, a1y = o1[t].y * fac,
              a1z = o1[t].z * fac, a1w = o1[t].w * fac;
#pragma unroll
        for (int off = 8; off <= 32; off <<= 1) {
            a0x += __shfl_xor(a0x, off); a0y += __shfl_xor(a0y, off);
            a0z += __shfl_xor(a0z, off); a0w += __shfl_xor(a0w, off);
            a1x += __shfl_xor(a1x, off); a1y += __shfl_xor(a1y, off);
            a1z += __shfl_xor(a1z, off); a1w += __shfl_xor(a1w, off);
        }
        if (r8 == 0) {
            *(float4*)&part_acc[((size_t)pidx * 4 + t) * HD_ + sub * 4] =
                make_float4(a0x, a0y, a0z, a0w);
            *(float4*)&part_acc[((size_t)pidx * 4 + t) * HD_ + 32 + sub * 4] =
                make_float4(a1x, a1y, a1z, a1w);
        }
        if (l == 0) {
            part_ml[pidx * 8 + t * 2 + 0] = M;
            part_ml[pidx * 8 + t * 2 + 1] = Lr;
        }
    }
}

// ---------------- merge partials + new tokens + normalize ----------------
__global__ __launch_bounds__(256) void merge_kernel(
    const float* __restrict__ part_ml, const float* __restrict__ part_acc,
    const float* __restrict__ qs, const float* __restrict__ kn,
    const float* __restrict__ vn,
    const unsigned char* __restrict__ mask8, const int* __restrict__ flag,
    float* __restrict__ attn_out)
{
    const int bh = blockIdx.x;
    const int b = bh >> 4, h = bh & 15;
    const int tid = threadIdx.x;
    const int t = tid >> 6, d = tid & 63;
    const int mode = *flag;
    const int* mask32 = (const int*)mask8;

    float M = NEGINF;
#pragma unroll
    for (int i = 0; i < 8; i++) M = fmaxf(M, part_ml[(bh * 8 + i) * 8 + t * 2]);
    float acc = 0.f, L = 0.f;
#pragma unroll
    for (int i = 0; i < 8; i++) {
        float mi = part_ml[(bh * 8 + i) * 8 + t * 2];
        float li = part_ml[(bh * 8 + i) * 8 + t * 2 + 1];
        if (mi > NEGINF) {
            float wgt = __expf(mi - M);
            L += li * wgt;
            acc += part_acc[((size_t)(bh * 8 + i) * 4 + t) * HD_ + d] * wgt;
        }
    }

    // new-token keys (positions CACHE_..CACHE_+3)
    float qv = qs[bh * 256 + t * 64 + d];
    float sn[4];
#pragma unroll
    for (int i = 0; i < 4; i++) {
        size_t mi_ = (size_t)b * S_ + CACHE_ + i;
        bool masked = mode ? (mask8[mi_] != 0) : (mask32[mi_] != 0);
        float prod = qv * kn[bh * 256 + i * 64 + d];
        prod += __shfl_xor(prod, 1);
        prod += __shfl_xor(prod, 2);
        prod += __shfl_xor(prod, 4);
        prod += __shfl_xor(prod, 8);
        prod += __shfl_xor(prod, 16);
        prod += __shfl_xor(prod, 32);
        sn[i] = masked ? NEGINF : prod;
    }
    float M2 = M;
#pragma unroll
    for (int i = 0; i < 4; i++) M2 = fmaxf(M2, sn[i]);
    if (M2 > NEGINF) {
        if (M > NEGINF) {
            float wo = __expf(M - M2);
            acc *= wo; L *= wo;
        }
#pragma unroll
        for (int i = 0; i < 4; i++) {
            if (sn[i] > NEGINF) {
                float e = __expf(sn[i] - M2);
                L += e;
                acc += e * vn[bh * 256 + i * 64 + d];
            }
        }
    }
    float o = (L > 0.f) ? acc / L : 0.f;
    attn_out[(size_t)(t * B_ + b) * E_ + h * HD_ + d] = o;
}

// ---------------- output projection (f32 -> f32) ----------------
__global__ __launch_bounds__(256) void oproj_kernel(
    const float* __restrict__ A,
    const float* __restrict__ W, const float* __restrict__ bias,
    float* __restrict__ out)
{
    __shared__ float A_l[64][33];
    __shared__ float W_l[16][33];
    const int bx = blockIdx.x;
    const int ct = bx >> 1, rt = bx & 1;
    const int c0 = ct * 16, r0 = rt * 64;
    const int tid = threadIdx.x;
    const int row = tid & 63, cg = tid >> 6;
    float acc[4] = {0.f, 0.f, 0.f, 0.f};

    for (int k0 = 0; k0 < 1024; k0 += 32) {
        __syncthreads();
        for (int j = tid; j < 512; j += 256) {
            int ar = j >> 3, kk = (j & 7) * 4;
            float4 v = *(const float4*)(A + (size_t)(r0 + ar) * 1024 + k0 + kk);
            A_l[ar][kk] = v.x; A_l[ar][kk + 1] = v.y;
            A_l[ar][kk + 2] = v.z; A_l[ar][kk + 3] = v.w;
        }
        if (tid < 128) {
            int wr = tid >> 3, kk = (tid & 7) * 4;
            float4 v = *(const float4*)(W + (size_t)(c0 + wr) * 1024 + k0 + kk);
            W_l[wr][kk] = v.x; W_l[wr][kk + 1] = v.y;
            W_l[wr][kk + 2] = v.z; W_l[wr][kk + 3] = v.w;
        }
        __syncthreads();
#pragma unroll
        for (int kk = 0; kk < 32; kk++) {
            float a = A_l[row][kk];
#pragma unroll
            for (int j = 0; j < 4; j++) acc[j] += a * W_l[cg * 4 + j][kk];
        }
    }
    const int r = r0 + row;
#pragma unroll
    for (int j = 0; j < 4; j++) {
        int c = c0 + cg * 4 + j;
        out[(size_t)r * 1024 + c] = acc[j] + bias[c];
    }
}

extern "C" void kernel_launch(void* const* d_in, const int* in_sizes, int n_in,
                              void* d_out, int out_size, void* d_ws, size_t ws_size,
                              hipStream_t stream) {
    const float* query = (const float*)d_in[0];
    // d_in[1] = key: unused by the reference (k_new/v_new project from query)
    const unsigned char* mask = (const unsigned char*)d_in[2];
    const float* kcache = (const float*)d_in[3];
    const float* vcache = (const float*)d_in[4];
    const float* Wq = (const float*)d_in[5];
    const float* bq = (const float*)d_in[6];
    const float* Wk = (const float*)d_in[7];
    const float* bk = (const float*)d_in[8];
    const float* Wv = (const float*)d_in[9];
    const float* bv = (const float*)d_in[10];
    const float* Wo = (const float*)d_in[11];
    const float* bo = (const float*)d_in[12];

    char* ws = (char*)d_ws;
    float* qs   = (float*)(ws);                       // 512 KB
    float* kn   = (float*)(ws + ( 512ull << 10));     // 512 KB
    float* vn   = (float*)(ws + (1024ull << 10));     // 512 KB
    float* att  = (float*)(ws + (1536ull << 10));     // 512 KB
    int*   flag = (int*)  (ws + (2048ull << 10));     // 4 B
    float* pml  = (float*)(ws + (2049ull << 10));     // 128 KB
    float* pacc = (float*)(ws + (3072ull << 10));     // 4 MB

    detect_mask<<<1, 256, 0, stream>>>(mask, flag);
    proj_kernel<<<384, 256, 0, stream>>>(query, Wq, bq, Wk, bk, Wv, bv, qs, kn, vn);
    attn_kernel<<<512 * SPLIT_, 256, 0, stream>>>(kcache, vcache, qs, mask, flag, pml, pacc);
    merge_kernel<<<512, 256, 0, stream>>>(pml, pacc, qs, kn, vn, mask, flag, att);
    oproj_kernel<<<128, 256, 0, stream>>>(att, Wo, bo, (float*)d_out);
}

// Round 9
// 207.591 us; speedup vs baseline: 2.1267x; 2.1267x over previous
//
#include <hip/hip_runtime.h>

typedef unsigned int u32;
typedef unsigned long long u64;

#define T_ 4
#define B_ 32
#define E_ 1024
#define H_ 16
#define HD_ 64
#define CACHE_ 4096
#define S_ 4100
#define SPLIT_ 2
#define NEGINF (-__builtin_inff())

// ---------------- prep: blocks 0..31 = mask compaction; 32..1567 = QKV proj ----------------
// Compaction block b scans mask row b, writes cidx[b][.] / ccnt[b]; block 0 also
// publishes the mask-dtype flag (1 = bool bytes, 0 = int32) for merge_kernel.
// Proj blocks: 16x16 output tiles of the three GEMMs (512 blocks per matrix).
__global__ __launch_bounds__(256) void prep_kernel(
    const float* __restrict__ query,
    const float* __restrict__ Wq, const float* __restrict__ bq,
    const float* __restrict__ Wk, const float* __restrict__ bk,
    const float* __restrict__ Wv, const float* __restrict__ bv,
    const unsigned char* __restrict__ mask8,
    float* __restrict__ qs, float* __restrict__ kn, float* __restrict__ vn,
    int* __restrict__ cidx, int* __restrict__ ccnt, int* __restrict__ flag)
{
    const int tid = threadIdx.x;
    if (blockIdx.x < 32) {
        // ---------- compaction ----------
        const int b = blockIdx.x;
        const int w = tid >> 6, l = tid & 63;
        const int* mask32 = (const int*)mask8;
        __shared__ int cnt_s;
        __shared__ int wcnt[4];
        __shared__ int base_s;

        // local mode detection over first 8KB of the mask buffer
        int cnt = 0;
        for (int i = tid; i < 8192; i += 256) cnt += (mask8[i] != 0) ? 1 : 0;
#pragma unroll
        for (int off = 32; off; off >>= 1) cnt += __shfl_xor(cnt, off);
        if (tid == 0) { cnt_s = 0; base_s = 0; }
        __syncthreads();
        if (l == 0) atomicAdd(&cnt_s, cnt);
        __syncthreads();
        const int mode = (cnt_s > 2048) ? 1 : 0;
        if (b == 0 && tid == 0) *flag = mode;

        for (int s0 = 0; s0 < CACHE_; s0 += 256) {
            int s = s0 + tid;
            bool ok = mode ? (mask8[(size_t)b * S_ + s] == 0)
                           : (mask32[(size_t)b * S_ + s] == 0);
            u64 bal = __ballot(ok);
            int pre = (int)__popcll(bal & ((1ull << l) - 1));
            if (l == 0) wcnt[w] = (int)__popcll(bal);
            __syncthreads();
            int off = base_s;
#pragma unroll
            for (int i = 0; i < 4; i++) if (i < w) off += wcnt[i];
            if (ok) cidx[b * CACHE_ + off + pre] = s;
            __syncthreads();
            if (tid == 0) base_s += wcnt[0] + wcnt[1] + wcnt[2] + wcnt[3];
            __syncthreads();
        }
        if (tid == 0) ccnt[b] = base_s;
        return;
    }

    // ---------- QKV projection, 16x16 tiles ----------
    const int bx = blockIdx.x - 32;       // 0..1535
    const int mat = bx >> 9;              // 0..2 (512 blocks each)
    const int rem = bx & 511;
    const int rt = rem >> 6, ct = rem & 63;
    const int r0 = rt * 16, c0 = ct * 16;
    const float* W    = (mat == 0) ? Wq : (mat == 1) ? Wk : Wv;
    const float* bias = (mat == 0) ? bq : (mat == 1) ? bk : bv;

    __shared__ float A_l[16][33];
    __shared__ float W_l[16][33];
    const int r = tid >> 4, cc = tid & 15;
    float acc = 0.f;

    for (int k0 = 0; k0 < 1024; k0 += 32) {
        __syncthreads();
        if (tid < 128) {
            int ar = tid >> 3, kk = (tid & 7) * 4;
            float4 v = *(const float4*)(query + (size_t)(r0 + ar) * 1024 + k0 + kk);
            A_l[ar][kk] = v.x; A_l[ar][kk + 1] = v.y;
            A_l[ar][kk + 2] = v.z; A_l[ar][kk + 3] = v.w;
        } else {
            int t2 = tid - 128;
            int wr = t2 >> 3, kk = (t2 & 7) * 4;
            float4 v = *(const float4*)(W + (size_t)(c0 + wr) * 1024 + k0 + kk);
            W_l[wr][kk] = v.x; W_l[wr][kk + 1] = v.y;
            W_l[wr][kk + 2] = v.z; W_l[wr][kk + 3] = v.w;
        }
        __syncthreads();
#pragma unroll
        for (int kk = 0; kk < 32; kk++) acc += A_l[r][kk] * W_l[cc][kk];
    }
    const int row = r0 + r, col = c0 + cc;
    const int t = row >> 5, b = row & 31;
    const int h = col >> 6, d = col & 63;
    float val = acc + bias[col];
    size_t oidx = ((size_t)((b * H_ + h) * T_ + t)) * HD_ + d;
    if (mat == 0) qs[oidx] = val * 0.125f;
    else if (mat == 1) kn[oidx] = val;
    else vn[oidx] = val;
}

// ---------------- attention: 128B-transaction, lane-local-softmax flash decode ----------------
// (round-7 kernel, verbatim: compacted gather at ~3.4 TB/s effective)
__global__ __launch_bounds__(256, 4) void attn_kernel(
    const float* __restrict__ kcache, const float* __restrict__ vcache,
    const float* __restrict__ qs,
    const int* __restrict__ cidx, const int* __restrict__ ccnt,
    float* __restrict__ part_ml, float* __restrict__ part_acc)
{
    const int bid = blockIdx.x;
    const int bh = bid >> 1, split = bid & 1;
    const int b = bh >> 4;
    const int tid = threadIdx.x;
    const int w = tid >> 6, l = tid & 63;
    const int sub = l & 7, r8 = l >> 3;

    __shared__ float q_l[256];
    __shared__ int cidx_l[2048];

    const int cnt = ccnt[b];
    const int half = (cnt + 1) >> 1;
    const int lo = split * half;
    const int hi = min(cnt, lo + half);
    const int n = hi - lo;

    q_l[tid] = qs[bh * 256 + tid];
    for (int i = tid; i < n; i += 256) cidx_l[i] = cidx[b * CACHE_ + lo + i];
    __syncthreads();

    float4 qa[4], qb[4];
#pragma unroll
    for (int t = 0; t < 4; t++) {
        qa[t] = *(const float4*)&q_l[t * 64 + sub * 4];
        qb[t] = *(const float4*)&q_l[t * 64 + 32 + sub * 4];
    }

    float4 o0[4], o1[4];
#pragma unroll
    for (int t = 0; t < 4; t++) {
        o0[t] = make_float4(0.f, 0.f, 0.f, 0.f);
        o1[t] = make_float4(0.f, 0.f, 0.f, 0.f);
    }
    float m[4] = {NEGINF, NEGINF, NEGINF, NEGINF};
    float L[4] = {0.f, 0.f, 0.f, 0.f};

    const float* kb = kcache + (size_t)bh * (CACHE_ * HD_) + sub * 4;
    const float* vb = vcache + (size_t)bh * (CACHE_ * HD_) + sub * 4;

    const int nch = (n + 31) >> 5;        // 32 rows per block-chunk (8 per wave)
    const int pbase = w * 8 + r8;

    float4 kA0, kA1, vA0, vA1, kB0, kB1, vB0, vB1;

#define ISSUE(K0, K1, V0, V1, CC) {                                   \
        int idx_ = cidx_l[min(pbase + (CC) * 32, n - 1)];             \
        const float* kp_ = kb + ((size_t)idx_ << 6);                  \
        const float* vp_ = vb + ((size_t)idx_ << 6);                  \
        K0 = *(const float4*)kp_;  K1 = *(const float4*)(kp_ + 32);   \
        V0 = *(const float4*)vp_;  V1 = *(const float4*)(vp_ + 32);   \
    }

#define PROCESS(K0, K1, V0, V1, CC) {                                               \
        const bool valid_ = ((CC) * 32 + pbase) < n;                                \
        _Pragma("unroll")                                                           \
        for (int t = 0; t < 4; t++) {                                               \
            float part = qa[t].x * K0.x + qa[t].y * K0.y + qa[t].z * K0.z           \
                       + qa[t].w * K0.w + qb[t].x * K1.x + qb[t].y * K1.y           \
                       + qb[t].z * K1.z + qb[t].w * K1.w;                           \
            part += __shfl_xor(part, 1);                                            \
            part += __shfl_xor(part, 2);                                            \
            part += __shfl_xor(part, 4);                                            \
            float s = valid_ ? part : NEGINF;                                       \
            if (s > m[t] + 8.f) {       /* defer-max: rare rescale */               \
                float fac = __expf(m[t] - s);                                       \
                L[t] *= fac;                                                        \
                o0[t].x *= fac; o0[t].y *= fac; o0[t].z *= fac; o0[t].w *= fac;     \
                o1[t].x *= fac; o1[t].y *= fac; o1[t].z *= fac; o1[t].w *= fac;     \
                m[t] = s;                                                           \
            }                                                                       \
            float e = (s == NEGINF) ? 0.f : __expf(s - m[t]);                       \
            L[t] += e;                                                              \
            o0[t].x += e * V0.x; o0[t].y += e * V0.y;                               \
            o0[t].z += e * V0.z; o0[t].w += e * V0.w;                               \
            o1[t].x += e * V1.x; o1[t].y += e * V1.y;                               \
            o1[t].z += e * V1.z; o1[t].w += e * V1.w;                               \
        }                                                                           \
    }

    if (nch > 0) ISSUE(kA0, kA1, vA0, vA1, 0);
    if (nch > 1) ISSUE(kB0, kB1, vB0, vB1, 1);

    for (int c = 0; c < nch; c += 2) {
        PROCESS(kA0, kA1, vA0, vA1, c);
        if (c + 2 < nch) ISSUE(kA0, kA1, vA0, vA1, c + 2);
        if (c + 1 < nch) {
            PROCESS(kB0, kB1, vB0, vB1, c + 1);
            if (c + 3 < nch) ISSUE(kB0, kB1, vB0, vB1, c + 3);
        }
    }
#undef ISSUE
#undef PROCESS

    const int pidx = bid * 4 + w;           // [0, 4096)
#pragma unroll
    for (int t = 0; t < 4; t++) {
        float M = m[t];
        M = fmaxf(M, __shfl_xor(M, 8));
        M = fmaxf(M, __shfl_xor(M, 16));
        M = fmaxf(M, __shfl_xor(M, 32));
        float fac = (m[t] == NEGINF) ? 0.f : __expf(m[t] - M);
        float Lr = L[t] * fac;
        Lr += __shfl_xor(Lr, 8);
        Lr += __shfl_xor(Lr, 16);
        Lr += __shfl_xor(Lr, 32);
        float a0x = o0[t].x * fac, a0y = o0[t].y * fac,
              a0z = o0[t].z * fac, a0w = o0[t].w * fac;
        float a1x = o1[t].x * fac, a1y = o1[t].y * fac,
              a1z = o1[t].z * fac, a1w = o1[t].w * fac;
#pragma unroll
        for (int off = 8; off <= 32; off <<= 1) {
            a0x += __shfl_xor(a0x, off); a0y += __shfl_xor(a0y, off);
            a0z += __shfl_xor(a0z, off); a0w += __shfl_xor(a0w, off);
            a1x += __shfl_xor(a1x, off); a1y += __shfl_xor(a1y, off);
            a1z += __shfl_xor(a1z, off); a1w += __shfl_xor(a1w, off);
        }
        if (r8 == 0) {
            *(float4*)&part_acc[((size_t)pidx * 4 + t) * HD_ + sub * 4] =
                make_float4(a0x, a0y, a0z, a0w);
            *(float4*)&part_acc[((size_t)pidx * 4 + t) * HD_ + 32 + sub * 4] =
                make_float4(a1x, a1y, a1z, a1w);
        }
        if (l == 0) {
            part_ml[pidx * 8 + t * 2 + 0] = M;
            part_ml[pidx * 8 + t * 2 + 1] = Lr;
        }
    }
}

// ---------------- merge partials + new tokens + normalize ----------------
__global__ __launch_bounds__(256) void merge_kernel(
    const float* __restrict__ part_ml, const float* __restrict__ part_acc,
    const float* __restrict__ qs, const float* __restrict__ kn,
    const float* __restrict__ vn,
    const unsigned char* __restrict__ mask8, const int* __restrict__ flag,
    float* __restrict__ attn_out)
{
    const int bh = blockIdx.x;
    const int b = bh >> 4, h = bh & 15;
    const int tid = threadIdx.x;
    const int t = tid >> 6, d = tid & 63;
    const int mode = *flag;
    const int* mask32 = (const int*)mask8;

    float M = NEGINF;
#pragma unroll
    for (int i = 0; i < 8; i++) M = fmaxf(M, part_ml[(bh * 8 + i) * 8 + t * 2]);
    float acc = 0.f, L = 0.f;
#pragma unroll
    for (int i = 0; i < 8; i++) {
        float mi = part_ml[(bh * 8 + i) * 8 + t * 2];
        float li = part_ml[(bh * 8 + i) * 8 + t * 2 + 1];
        if (mi > NEGINF) {
            float wgt = __expf(mi - M);
            L += li * wgt;
            acc += part_acc[((size_t)(bh * 8 + i) * 4 + t) * HD_ + d] * wgt;
        }
    }

    float qv = qs[bh * 256 + t * 64 + d];
    float sn[4];
#pragma unroll
    for (int i = 0; i < 4; i++) {
        size_t mi_ = (size_t)b * S_ + CACHE_ + i;
        bool masked = mode ? (mask8[mi_] != 0) : (mask32[mi_] != 0);
        float prod = qv * kn[bh * 256 + i * 64 + d];
        prod += __shfl_xor(prod, 1);
        prod += __shfl_xor(prod, 2);
        prod += __shfl_xor(prod, 4);
        prod += __shfl_xor(prod, 8);
        prod += __shfl_xor(prod, 16);
        prod += __shfl_xor(prod, 32);
        sn[i] = masked ? NEGINF : prod;
    }
    float M2 = M;
#pragma unroll
    for (int i = 0; i < 4; i++) M2 = fmaxf(M2, sn[i]);
    if (M2 > NEGINF) {
        if (M > NEGINF) {
            float wo = __expf(M - M2);
            acc *= wo; L *= wo;
        }
#pragma unroll
        for (int i = 0; i < 4; i++) {
            if (sn[i] > NEGINF) {
                float e = __expf(sn[i] - M2);
                L += e;
                acc += e * vn[bh * 256 + i * 64 + d];
            }
        }
    }
    float o = (L > 0.f) ? acc / L : 0.f;
    attn_out[(size_t)(t * B_ + b) * E_ + h * HD_ + d] = o;
}

// ---------------- output projection, 16x16 tiles (512 blocks) ----------------
__global__ __launch_bounds__(256) void oproj_kernel(
    const float* __restrict__ A,
    const float* __restrict__ W, const float* __restrict__ bias,
    float* __restrict__ out)
{
    const int bx = blockIdx.x;            // 512 blocks: 8 rt x 64 ct
    const int rt = bx >> 6, ct = bx & 63;
    const int r0 = rt * 16, c0 = ct * 16;
    const int tid = threadIdx.x;

    __shared__ float A_l[16][33];
    __shared__ float W_l[16][33];
    const int r = tid >> 4, cc = tid & 15;
    float acc = 0.f;

    for (int k0 = 0; k0 < 1024; k0 += 32) {
        __syncthreads();
        if (tid < 128) {
            int ar = tid >> 3, kk = (tid & 7) * 4;
            float4 v = *(const float4*)(A + (size_t)(r0 + ar) * 1024 + k0 + kk);
            A_l[ar][kk] = v.x; A_l[ar][kk + 1] = v.y;
            A_l[ar][kk + 2] = v.z; A_l[ar][kk + 3] = v.w;
        } else {
            int t2 = tid - 128;
            int wr = t2 >> 3, kk = (t2 & 7) * 4;
            float4 v = *(const float4*)(W + (size_t)(c0 + wr) * 1024 + k0 + kk);
            W_l[wr][kk] = v.x; W_l[wr][kk + 1] = v.y;
            W_l[wr][kk + 2] = v.z; W_l[wr][kk + 3] = v.w;
        }
        __syncthreads();
#pragma unroll
        for (int kk = 0; kk < 32; kk++) acc += A_l[r][kk] * W_l[cc][kk];
    }
    const int row = r0 + r, col = c0 + cc;
    out[(size_t)row * 1024 + col] = acc + bias[col];
}

extern "C" void kernel_launch(void* const* d_in, const int* in_sizes, int n_in,
                              void* d_out, int out_size, void* d_ws, size_t ws_size,
                              hipStream_t stream) {
    const float* query = (const float*)d_in[0];
    // d_in[1] = key: unused by the reference (k_new/v_new project from query)
    const unsigned char* mask = (const unsigned char*)d_in[2];
    const float* kcache = (const float*)d_in[3];
    const float* vcache = (const float*)d_in[4];
    const float* Wq = (const float*)d_in[5];
    const float* bq = (const float*)d_in[6];
    const float* Wk = (const float*)d_in[7];
    const float* bk = (const float*)d_in[8];
    const float* Wv = (const float*)d_in[9];
    const float* bv = (const float*)d_in[10];
    const float* Wo = (const float*)d_in[11];
    const float* bo = (const float*)d_in[12];

    char* ws = (char*)d_ws;
    float* qs   = (float*)(ws);                       // 512 KB
    float* kn   = (float*)(ws + ( 512ull << 10));     // 512 KB
    float* vn   = (float*)(ws + (1024ull << 10));     // 512 KB
    float* att  = (float*)(ws + (1536ull << 10));     // 512 KB
    int*   flag = (int*)  (ws + (2048ull << 10));     // 4 B
    int*   cidx = (int*)  (ws + (2049ull << 10));     // 512 KB
    int*   ccnt = (int*)  (ws + (2562ull << 10));     // 128 B
    float* pml  = (float*)(ws + (2563ull << 10));     // 128 KB
    float* pacc = (float*)(ws + (3072ull << 10));     // 4 MB

    prep_kernel<<<32 + 1536, 256, 0, stream>>>(query, Wq, bq, Wk, bk, Wv, bv,
                                               mask, qs, kn, vn, cidx, ccnt, flag);
    attn_kernel<<<512 * SPLIT_, 256, 0, stream>>>(kcache, vcache, qs, cidx, ccnt, pml, pacc);
    merge_kernel<<<512, 256, 0, stream>>>(pml, pacc, qs, kn, vn, mask, flag, att);
    oproj_kernel<<<512, 256, 0, stream>>>(att, Wo, bo, (float*)d_out);
}

// Round 11
// 179.876 us; speedup vs baseline: 2.4544x; 1.1541x over previous
//
#include <hip/hip_runtime.h>

typedef unsigned int u32;
typedef unsigned long long u64;
typedef float f32x4 __attribute__((ext_vector_type(4)));

#define T_ 4
#define B_ 32
#define E_ 1024
#define H_ 16
#define HD_ 64
#define CACHE_ 4096
#define S_ 4100
#define SPLIT_ 2
#define NEGINF (-__builtin_inff())

// ---------------- prep: blocks 0..31 = mask compaction; 32..1567 = QKV proj ----------------
__global__ __launch_bounds__(256) void prep_kernel(
    const float* __restrict__ query,
    const float* __restrict__ Wq, const float* __restrict__ bq,
    const float* __restrict__ Wk, const float* __restrict__ bk,
    const float* __restrict__ Wv, const float* __restrict__ bv,
    const unsigned char* __restrict__ mask8,
    float* __restrict__ qs, float* __restrict__ kn, float* __restrict__ vn,
    int* __restrict__ cidx, int* __restrict__ ccnt, int* __restrict__ flag)
{
    const int tid = threadIdx.x;
    if (blockIdx.x < 32) {
        // ---------- compaction ----------
        const int b = blockIdx.x;
        const int w = tid >> 6, l = tid & 63;
        const int* mask32 = (const int*)mask8;
        __shared__ int cnt_s;
        __shared__ int wcnt[4];
        __shared__ int base_s;

        int cnt = 0;
        for (int i = tid; i < 8192; i += 256) cnt += (mask8[i] != 0) ? 1 : 0;
#pragma unroll
        for (int off = 32; off; off >>= 1) cnt += __shfl_xor(cnt, off);
        if (tid == 0) { cnt_s = 0; base_s = 0; }
        __syncthreads();
        if (l == 0) atomicAdd(&cnt_s, cnt);
        __syncthreads();
        const int mode = (cnt_s > 2048) ? 1 : 0;
        if (b == 0 && tid == 0) *flag = mode;

        for (int s0 = 0; s0 < CACHE_; s0 += 256) {
            int s = s0 + tid;
            bool ok = mode ? (mask8[(size_t)b * S_ + s] == 0)
                           : (mask32[(size_t)b * S_ + s] == 0);
            u64 bal = __ballot(ok);
            int pre = (int)__popcll(bal & ((1ull << l) - 1));
            if (l == 0) wcnt[w] = (int)__popcll(bal);
            __syncthreads();
            int off = base_s;
#pragma unroll
            for (int i = 0; i < 4; i++) if (i < w) off += wcnt[i];
            if (ok) cidx[b * CACHE_ + off + pre] = s;
            __syncthreads();
            if (tid == 0) base_s += wcnt[0] + wcnt[1] + wcnt[2] + wcnt[3];
            __syncthreads();
        }
        if (tid == 0) ccnt[b] = base_s;
        return;
    }

    // ---------- QKV projection, 16x16 tiles, BK=64 ----------
    const int bx = blockIdx.x - 32;       // 0..1535
    const int mat = bx >> 9;              // 0..2 (512 blocks each)
    const int rem = bx & 511;
    const int rt = rem >> 6, ct = rem & 63;
    const int r0 = rt * 16, c0 = ct * 16;
    const float* W    = (mat == 0) ? Wq : (mat == 1) ? Wk : Wv;
    const float* bias = (mat == 0) ? bq : (mat == 1) ? bk : bv;

    __shared__ float A_l[16][65];
    __shared__ float W_l[16][65];
    const int r = tid >> 4, cc = tid & 15;
    float acc = 0.f;

    for (int k0 = 0; k0 < 1024; k0 += 64) {
        __syncthreads();
        if (tid < 128) {
            int j0 = tid * 2;
#pragma unroll
            for (int jj = 0; jj < 2; jj++) {
                int j = j0 + jj;
                int ar = j >> 4, kk = (j & 15) * 4;
                float4 v = *(const float4*)(query + (size_t)(r0 + ar) * 1024 + k0 + kk);
                A_l[ar][kk] = v.x; A_l[ar][kk + 1] = v.y;
                A_l[ar][kk + 2] = v.z; A_l[ar][kk + 3] = v.w;
            }
        } else {
            int j0 = (tid - 128) * 2;
#pragma unroll
            for (int jj = 0; jj < 2; jj++) {
                int j = j0 + jj;
                int wr = j >> 4, kk = (j & 15) * 4;
                float4 v = *(const float4*)(W + (size_t)(c0 + wr) * 1024 + k0 + kk);
                W_l[wr][kk] = v.x; W_l[wr][kk + 1] = v.y;
                W_l[wr][kk + 2] = v.z; W_l[wr][kk + 3] = v.w;
            }
        }
        __syncthreads();
#pragma unroll
        for (int kk = 0; kk < 64; kk++) acc += A_l[r][kk] * W_l[cc][kk];
    }
    const int row = r0 + r, col = c0 + cc;
    const int t = row >> 5, b = row & 31;
    const int h = col >> 6, d = col & 63;
    float val = acc + bias[col];
    size_t oidx = ((size_t)((b * H_ + h) * T_ + t)) * HD_ + d;
    if (mat == 0) qs[oidx] = val * 0.125f;
    else if (mat == 1) kn[oidx] = val;
    else vn[oidx] = val;
}

// ---------------- attention: 128B-transaction, lane-local-softmax flash decode ----------------
// round-7 structure; K/V loads switched to non-temporal (zero-reuse stream,
// evict-first in L1/L2 -> less cache queuing for the gather).
__global__ __launch_bounds__(256, 4) void attn_kernel(
    const float* __restrict__ kcache, const float* __restrict__ vcache,
    const float* __restrict__ qs,
    const int* __restrict__ cidx, const int* __restrict__ ccnt,
    float* __restrict__ part_ml, float* __restrict__ part_acc)
{
    const int bid = blockIdx.x;
    const int bh = bid >> 1, split = bid & 1;
    const int b = bh >> 4;
    const int tid = threadIdx.x;
    const int w = tid >> 6, l = tid & 63;
    const int sub = l & 7, r8 = l >> 3;

    __shared__ float q_l[256];
    __shared__ int cidx_l[2048];

    const int cnt = ccnt[b];
    const int half = (cnt + 1) >> 1;
    const int lo = split * half;
    const int hi = min(cnt, lo + half);
    const int n = hi - lo;

    q_l[tid] = qs[bh * 256 + tid];
    for (int i = tid; i < n; i += 256) cidx_l[i] = cidx[b * CACHE_ + lo + i];
    __syncthreads();

    float4 qa[4], qb[4];
#pragma unroll
    for (int t = 0; t < 4; t++) {
        qa[t] = *(const float4*)&q_l[t * 64 + sub * 4];
        qb[t] = *(const float4*)&q_l[t * 64 + 32 + sub * 4];
    }

    float4 o0[4], o1[4];
#pragma unroll
    for (int t = 0; t < 4; t++) {
        o0[t] = make_float4(0.f, 0.f, 0.f, 0.f);
        o1[t] = make_float4(0.f, 0.f, 0.f, 0.f);
    }
    float m[4] = {NEGINF, NEGINF, NEGINF, NEGINF};
    float L[4] = {0.f, 0.f, 0.f, 0.f};

    const float* kb = kcache + (size_t)bh * (CACHE_ * HD_) + sub * 4;
    const float* vb = vcache + (size_t)bh * (CACHE_ * HD_) + sub * 4;

    const int nch = (n + 31) >> 5;        // 32 rows per block-chunk (8 per wave)
    const int pbase = w * 8 + r8;

    f32x4 kA0, kA1, vA0, vA1, kB0, kB1, vB0, vB1;

#define ISSUE(K0, K1, V0, V1, CC) {                                       \
        int idx_ = cidx_l[min(pbase + (CC) * 32, n - 1)];                  \
        const f32x4* kp_ = (const f32x4*)(kb + ((size_t)idx_ << 6));       \
        const f32x4* vp_ = (const f32x4*)(vb + ((size_t)idx_ << 6));       \
        K0 = __builtin_nontemporal_load(kp_);                              \
        K1 = __builtin_nontemporal_load(kp_ + 8);                          \
        V0 = __builtin_nontemporal_load(vp_);                              \
        V1 = __builtin_nontemporal_load(vp_ + 8);                          \
    }

#define PROCESS(K0, K1, V0, V1, CC) {                                               \
        const bool valid_ = ((CC) * 32 + pbase) < n;                                \
        _Pragma("unroll")                                                           \
        for (int t = 0; t < 4; t++) {                                               \
            float part = qa[t].x * K0.x + qa[t].y * K0.y + qa[t].z * K0.z           \
                       + qa[t].w * K0.w + qb[t].x * K1.x + qb[t].y * K1.y           \
                       + qb[t].z * K1.z + qb[t].w * K1.w;                           \
            part += __shfl_xor(part, 1);                                            \
            part += __shfl_xor(part, 2);                                            \
            part += __shfl_xor(part, 4);                                            \
            float s = valid_ ? part : NEGINF;                                       \
            if (s > m[t] + 8.f) {       /* defer-max: rare rescale */               \
                float fac = __expf(m[t] - s);                                       \
                L[t] *= fac;                                                        \
                o0[t].x *= fac; o0[t].y *= fac; o0[t].z *= fac; o0[t].w *= fac;     \
                o1[t].x *= fac; o1[t].y *= fac; o1[t].z *= fac; o1[t].w *= fac;     \
                m[t] = s;                                                           \
            }                                                                       \
            float e = (s == NEGINF) ? 0.f : __expf(s - m[t]);                       \
            L[t] += e;                                                              \
            o0[t].x += e * V0.x; o0[t].y += e * V0.y;                               \
            o0[t].z += e * V0.z; o0[t].w += e * V0.w;                               \
            o1[t].x += e * V1.x; o1[t].y += e * V1.y;                               \
            o1[t].z += e * V1.z; o1[t].w += e * V1.w;                               \
        }                                                                           \
    }

    if (nch > 0) ISSUE(kA0, kA1, vA0, vA1, 0);
    if (nch > 1) ISSUE(kB0, kB1, vB0, vB1, 1);

    for (int c = 0; c < nch; c += 2) {
        PROCESS(kA0, kA1, vA0, vA1, c);
        if (c + 2 < nch) ISSUE(kA0, kA1, vA0, vA1, c + 2);
        if (c + 1 < nch) {
            PROCESS(kB0, kB1, vB0, vB1, c + 1);
            if (c + 3 < nch) ISSUE(kB0, kB1, vB0, vB1, c + 3);
        }
    }
#undef ISSUE
#undef PROCESS

    const int pidx = bid * 4 + w;           // [0, 4096)
#pragma unroll
    for (int t = 0; t < 4; t++) {
        float M = m[t];
        M = fmaxf(M, __shfl_xor(M, 8));
        M = fmaxf(M, __shfl_xor(M, 16));
        M = fmaxf(M, __shfl_xor(M, 32));
        float fac = (m[t] == NEGINF) ? 0.f : __expf(m[t] - M);
        float Lr = L[t] * fac;
        Lr += __shfl_xor(Lr, 8);
        Lr += __shfl_xor(Lr, 16);
        Lr += __shfl_xor(Lr, 32);
        float a0x = o0[t].x * fac, a0y = o0[t].y * fac,
              a0z = o0[t].z * fac, a0w = o0[t].w * fac;
        float a1x = o1[t].x * fac, a1y = o1[t].y * fac,
              a1z = o1[t].z * fac, a1w = o1[t].w * fac;
#pragma unroll
        for (int off = 8; off <= 32; off <<= 1) {
            a0x += __shfl_xor(a0x, off); a0y += __shfl_xor(a0y, off);
            a0z += __shfl_xor(a0z, off); a0w += __shfl_xor(a0w, off);
            a1x += __shfl_xor(a1x, off); a1y += __shfl_xor(a1y, off);
            a1z += __shfl_xor(a1w, off) * 0.f + __shfl_xor(a1z, off);
            a1w += __shfl_xor(a1w, off);
        }
        if (r8 == 0) {
            *(float4*)&part_acc[((size_t)pidx * 4 + t) * HD_ + sub * 4] =
                make_float4(a0x, a0y, a0z, a0w);
            *(float4*)&part_acc[((size_t)pidx * 4 + t) * HD_ + 32 + sub * 4] =
                make_float4(a1x, a1y, a1z, a1w);
        }
        if (l == 0) {
            part_ml[pidx * 8 + t * 2 + 0] = M;
            part_ml[pidx * 8 + t * 2 + 1] = Lr;
        }
    }
}

// ---------------- merge partials + new tokens + normalize ----------------
__global__ __launch_bounds__(256) void merge_kernel(
    const float* __restrict__ part_ml, const float* __restrict__ part_acc,
    const float* __restrict__ qs, const float* __restrict__ kn,
    const float* __restrict__ vn,
    const unsigned char* __restrict__ mask8, const int* __restrict__ flag,
    float* __restrict__ attn_out)
{
    const int bh = blockIdx.x;
    const int b = bh >> 4, h = bh & 15;
    const int tid = threadIdx.x;
    const int t = tid >> 6, d = tid & 63;
    const int mode = *flag;
    const int* mask32 = (const int*)mask8;

    float M = NEGINF;
#pragma unroll
    for (int i = 0; i < 8; i++) M = fmaxf(M, part_ml[(bh * 8 + i) * 8 + t * 2]);
    float acc = 0.f, L = 0.f;
#pragma unroll
    for (int i = 0; i < 8; i++) {
        float mi = part_ml[(bh * 8 + i) * 8 + t * 2];
        float li = part_ml[(bh * 8 + i) * 8 + t * 2 + 1];
        if (mi > NEGINF) {
            float wgt = __expf(mi - M);
            L += li * wgt;
            acc += part_acc[((size_t)(bh * 8 + i) * 4 + t) * HD_ + d] * wgt;
        }
    }

    float qv = qs[bh * 256 + t * 64 + d];
    float sn[4];
#pragma unroll
    for (int i = 0; i < 4; i++) {
        size_t mi_ = (size_t)b * S_ + CACHE_ + i;
        bool masked = mode ? (mask8[mi_] != 0) : (mask32[mi_] != 0);
        float prod = qv * kn[bh * 256 + i * 64 + d];
        prod += __shfl_xor(prod, 1);
        prod += __shfl_xor(prod, 2);
        prod += __shfl_xor(prod, 4);
        prod += __shfl_xor(prod, 8);
        prod += __shfl_xor(prod, 16);
        prod += __shfl_xor(prod, 32);
        sn[i] = masked ? NEGINF : prod;
    }
    float M2 = M;
#pragma unroll
    for (int i = 0; i < 4; i++) M2 = fmaxf(M2, sn[i]);
    if (M2 > NEGINF) {
        if (M > NEGINF) {
            float wo = __expf(M - M2);
            acc *= wo; L *= wo;
        }
#pragma unroll
        for (int i = 0; i < 4; i++) {
            if (sn[i] > NEGINF) {
                float e = __expf(sn[i] - M2);
                L += e;
                acc += e * vn[bh * 256 + i * 64 + d];
            }
        }
    }
    float o = (L > 0.f) ? acc / L : 0.f;
    attn_out[(size_t)(t * B_ + b) * E_ + h * HD_ + d] = o;
}

// ---------------- output projection, 16x16 tiles, BK=64 (512 blocks) ----------------
__global__ __launch_bounds__(256) void oproj_kernel(
    const float* __restrict__ A,
    const float* __restrict__ W, const float* __restrict__ bias,
    float* __restrict__ out)
{
    const int bx = blockIdx.x;            // 512 blocks: 8 rt x 64 ct
    const int rt = bx >> 6, ct = bx & 63;
    const int r0 = rt * 16, c0 = ct * 16;
    const int tid = threadIdx.x;

    __shared__ float A_l[16][65];
    __shared__ float W_l[16][65];
    const int r = tid >> 4, cc = tid & 15;
    float acc = 0.f;

    for (int k0 = 0; k0 < 1024; k0 += 64) {
        __syncthreads();
        if (tid < 128) {
            int j0 = tid * 2;
#pragma unroll
            for (int jj = 0; jj < 2; jj++) {
                int j = j0 + jj;
                int ar = j >> 4, kk = (j & 15) * 4;
                float4 v = *(const float4*)(A + (size_t)(r0 + ar) * 1024 + k0 + kk);
                A_l[ar][kk] = v.x; A_l[ar][kk + 1] = v.y;
                A_l[ar][kk + 2] = v.z; A_l[ar][kk + 3] = v.w;
            }
        } else {
            int j0 = (tid - 128) * 2;
#pragma unroll
            for (int jj = 0; jj < 2; jj++) {
                int j = j0 + jj;
                int wr = j >> 4, kk = (j & 15) * 4;
                float4 v = *(const float4*)(W + (size_t)(c0 + wr) * 1024 + k0 + kk);
                W_l[wr][kk] = v.x; W_l[wr][kk + 1] = v.y;
                W_l[wr][kk + 2] = v.z; W_l[wr][kk + 3] = v.w;
            }
        }
        __syncthreads();
#pragma unroll
        for (int kk = 0; kk < 64; kk++) acc += A_l[r][kk] * W_l[cc][kk];
    }
    const int row = r0 + r, col = c0 + cc;
    out[(size_t)row * 1024 + col] = acc + bias[col];
}

extern "C" void kernel_launch(void* const* d_in, const int* in_sizes, int n_in,
                              void* d_out, int out_size, void* d_ws, size_t ws_size,
                              hipStream_t stream) {
    const float* query = (const float*)d_in[0];
    // d_in[1] = key: unused by the reference (k_new/v_new project from query)
    const unsigned char* mask = (const unsigned char*)d_in[2];
    const float* kcache = (const float*)d_in[3];
    const float* vcache = (const float*)d_in[4];
    const float* Wq = (const float*)d_in[5];
    const float* bq = (const float*)d_in[6];
    const float* Wk = (const float*)d_in[7];
    const float* bk = (const float*)d_in[8];
    const float* Wv = (const float*)d_in[9];
    const float* bv = (const float*)d_in[10];
    const float* Wo = (const float*)d_in[11];
    const float* bo = (const float*)d_in[12];

    char* ws = (char*)d_ws;
    float* qs   = (float*)(ws);                       // 512 KB
    float* kn   = (float*)(ws + ( 512ull << 10));     // 512 KB
    float* vn   = (float*)(ws + (1024ull << 10));     // 512 KB
    float* att  = (float*)(ws + (1536ull << 10));     // 512 KB
    int*   flag = (int*)  (ws + (2048ull << 10));     // 4 B
    int*   cidx = (int*)  (ws + (2049ull << 10));     // 512 KB
    int*   ccnt = (int*)  (ws + (2562ull << 10));     // 128 B
    float* pml  = (float*)(ws + (2563ull << 10));     // 128 KB
    float* pacc = (float*)(ws + (3072ull << 10));     // 4 MB

    prep_kernel<<<32 + 1536, 256, 0, stream>>>(query, Wq, bq, Wk, bk, Wv, bv,
                                               mask, qs, kn, vn, cidx, ccnt, flag);
    attn_kernel<<<512 * SPLIT_, 256, 0, stream>>>(kcache, vcache, qs, cidx, ccnt, pml, pacc);
    merge_kernel<<<512, 256, 0, stream>>>(pml, pacc, qs, kn, vn, mask, flag, att);
    oproj_kernel<<<512, 256, 0, stream>>>(att, Wo, bo, (float*)d_out);
}